// Round 14
// baseline (95.050 us; speedup 1.0000x reference)
//
#include <hip/hip_runtime.h>
#include <hip/hip_bf16.h>
#include <cstdint>

#define LEAKY 0.2f
#define EPSF 1e-7f

// ---- binned path (n <= 65536) ----
#define BINSHIFT 9
#define BINSZ 512
#define MAXBINS 128
#define BCAP 10240           // per-bin edge capacity (mean 8192, sd ~90)
#define TILE 4096            // edges per P1 block (16/thread)
#define SPLIT 32             // P2 blocks per bin
#define NPB 16               // nodes per P2 block
#define CAP 64               // per-node degree cap

// ---- fallback path (n > 65536) ----
#define EILP 8

typedef __attribute__((ext_vector_type(8))) _Float16 f16x8;
typedef __attribute__((ext_vector_type(4))) float f32x4;

__device__ __forceinline__ unsigned short f2bf(float x) {
    return __bfloat16_as_ushort(__float2bfloat16(x));
}
__device__ __forceinline__ unsigned short f2h_bits(float x) {
    union { _Float16 h; unsigned short s; } c; c.h = (_Float16)x; return c.s;
}

// =================== K1: Wt16 = fp16(W^T) + cursors + dtype detect ================
__global__ __launch_bounds__(256) void init_kernel(const float* __restrict__ W,
                                                   const unsigned int* __restrict__ w,
                                                   int n_pairs,
                                                   unsigned short* __restrict__ Wt16,
                                                   int* __restrict__ bin_cursor,
                                                   int* __restrict__ flag) {
    int idx = blockIdx.x * 256 + threadIdx.x;       // 0..16383
    int kk = idx >> 7, nn = idx & 127;
    Wt16[nn * 128 + kk] = f2h_bits(W[kk * 128 + nn]);
    if (blockIdx.x == 0) {
        __shared__ int any_sh;
        int t = threadIdx.x;
        if (t < MAXBINS) bin_cursor[t] = 0;
        if (t == 0) any_sh = 0;
        __syncthreads();
        unsigned int acc = 0;
        int lim = n_pairs < 8192 ? n_pairs : 8192;
        for (int k = t; k < lim; k += 256) acc |= w[2 * k + 1];
        if (__any(acc != 0)) { if ((t & 63) == 0) any_sh = 1; }
        __syncthreads();
        if (t == 0) *flag = any_sh ? 1 : 0;         // int64 edges: zero high halves -> 0
    }
}

// =================== K2: fused fp16-MFMA GEMM (blocks [0,gb)) + P1 binning ========
// P1 path is EXACTLY the twice-proven (R9-benched, absmax 0.0039) version.
__global__ __launch_bounds__(256) void gemm_p1_kernel(const float* __restrict__ X,
                                                      const unsigned short* __restrict__ Wt16,
                                                      const float* __restrict__ ka,
                                                      unsigned short* __restrict__ h16,
                                                      float* __restrict__ a,
                                                      float* __restrict__ b, int n,
                                                      const void* __restrict__ eraw,
                                                      const int* __restrict__ flag,
                                                      unsigned int* __restrict__ binbuf,
                                                      int* __restrict__ bin_cursor,
                                                      int E, int nbins, int gemm_blocks) {
    __shared__ union {
        struct {
            unsigned int staged[TILE];                                              // 16384 B
            int hist[MAXBINS], sbase[MAXBINS], scur[MAXBINS], gpos[MAXBINS];        // 2048 B
        } p1;
        float abred[4][32][2];                                                      // 1024 B
    } sh;

    int t = threadIdx.x;

    if ((int)blockIdx.x >= gemm_blocks) {
        // ---------------- P1: partition edges into bins, coalesced output ---------
        int pb = (int)blockIdx.x - gemm_blocks;
        int tile0 = pb * TILE;
        int cnt_t = E - tile0; if (cnt_t > TILE) cnt_t = TILE; if (cnt_t < 0) cnt_t = 0;
        bool e32 = (*flag != 0);

        for (int i = t; i < MAXBINS; i += 256) sh.p1.hist[i] = 0;
        __syncthreads();

        unsigned int rec[16]; int bn[16];
        #pragma unroll
        for (int k = 0; k < 16; ++k) {
            int ofs = t + k * 256;
            bn[k] = -1;
            if (ofs < cnt_t) {
                int e = tile0 + ofs;
                unsigned int tgt, nbr;
                if (e32) {
                    uint2 q = ((const uint2*)eraw)[e];
                    tgt = q.x; nbr = q.y;
                } else {
                    uint4 q = ((const uint4*)eraw)[e];   // int64 pair: lows at x,z
                    tgt = q.x; nbr = q.z;
                }
                int bb = (int)(tgt >> BINSHIFT);
                rec[k] = ((unsigned int)bb << 25) | ((tgt & (BINSZ - 1)) << 16) | (nbr & 0xFFFFu);
                bn[k] = bb;
                atomicAdd(&sh.p1.hist[bb], 1);
            }
        }
        __syncthreads();

        if (t < 64) {    // exclusive scan over 128 bins, 2/lane
            int h0 = sh.p1.hist[t], h1 = sh.p1.hist[t + 64];
            int x0 = h0, x1 = h1;
            #pragma unroll
            for (int off = 1; off < 64; off <<= 1) {
                int y = __shfl_up(x0, off, 64); if (t >= off) x0 += y;
            }
            int tot0 = __shfl(x0, 63, 64);
            #pragma unroll
            for (int off = 1; off < 64; off <<= 1) {
                int y = __shfl_up(x1, off, 64); if (t >= off) x1 += y;
            }
            x1 += tot0;
            sh.p1.sbase[t] = x0 - h0;
            sh.p1.sbase[t + 64] = x1 - h1;
        }
        __syncthreads();
        if (t < MAXBINS) sh.p1.scur[t] = sh.p1.sbase[t];
        if (t < nbins) {
            int c = sh.p1.hist[t];
            sh.p1.gpos[t] = c ? atomicAdd(&bin_cursor[t], c) : 0;   // one atomic/bin/block
        }
        __syncthreads();

        #pragma unroll
        for (int k = 0; k < 16; ++k) {
            if (bn[k] >= 0) {
                int pos = atomicAdd(&sh.p1.scur[bn[k]], 1);
                sh.p1.staged[pos] = rec[k];
            }
        }
        __syncthreads();

        for (int i = t; i < cnt_t; i += 256) {
            unsigned int r = sh.p1.staged[i];
            int bb = (int)(r >> 25);
            int g = sh.p1.gpos[bb] + (i - sh.p1.sbase[bb]);
            if (g < BCAP) binbuf[(size_t)bb * BCAP + g] = r & 0x01FFFFFFu;
        }
        return;
    }

    // ---------- fp16 MFMA GEMM: 32 rows x 128 cols per block ----------
    // fp16 has 11 mantissa bits: input-quantization error ~8x below bf16.
    int brow = blockIdx.x * 32;
    int wv = t >> 6, l = t & 63, lr = l & 15, lg = l >> 4;
    int cb0 = wv * 32, cb1 = wv * 32 + 16;

    f32x4 acc[2][2] = {};   // [mt][ct]

    #pragma unroll
    for (int kk = 0; kk < 4; ++kk) {
        int kof = kk * 32 + lg * 8;
        f16x8 af[2];
        #pragma unroll
        for (int mt = 0; mt < 2; ++mt) {
            int row = brow + mt * 16 + lr;
            float4 x0 = make_float4(0.f, 0.f, 0.f, 0.f), x1 = x0;
            if (row < n) {
                x0 = *(const float4*)(X + (size_t)row * 128 + kof);
                x1 = *(const float4*)(X + (size_t)row * 128 + kof + 4);
            }
            f16x8 v;
            v[0] = (_Float16)x0.x; v[1] = (_Float16)x0.y;
            v[2] = (_Float16)x0.z; v[3] = (_Float16)x0.w;
            v[4] = (_Float16)x1.x; v[5] = (_Float16)x1.y;
            v[6] = (_Float16)x1.z; v[7] = (_Float16)x1.w;
            af[mt] = v;
        }
        f16x8 bf0 = *(const f16x8*)(Wt16 + (size_t)(cb0 + lr) * 128 + kof);
        f16x8 bf1 = *(const f16x8*)(Wt16 + (size_t)(cb1 + lr) * 128 + kof);
        acc[0][0] = __builtin_amdgcn_mfma_f32_16x16x32_f16(af[0], bf0, acc[0][0], 0, 0, 0);
        acc[0][1] = __builtin_amdgcn_mfma_f32_16x16x32_f16(af[0], bf1, acc[0][1], 0, 0, 0);
        acc[1][0] = __builtin_amdgcn_mfma_f32_16x16x32_f16(af[1], bf0, acc[1][0], 0, 0, 0);
        acc[1][1] = __builtin_amdgcn_mfma_f32_16x16x32_f16(af[1], bf1, acc[1][1], 0, 0, 0);
    }

    // epilogue: h16 store as fp16 (C/D: col=lane&15, row=(lane>>4)*4+reg) + a/b partials
    float ka10 = ka[cb0 + lr], ka11 = ka[cb1 + lr];
    float ka20 = ka[128 + cb0 + lr], ka21 = ka[128 + cb1 + lr];
    #pragma unroll
    for (int mt = 0; mt < 2; ++mt) {
        #pragma unroll
        for (int r = 0; r < 4; ++r) {
            int rloc = mt * 16 + lg * 4 + r;
            int row = brow + rloc;
            float h0 = acc[mt][0][r], h1 = acc[mt][1][r];
            if (row < n) {
                h16[(size_t)row * 128 + cb0 + lr] = f2h_bits(h0);
                h16[(size_t)row * 128 + cb1 + lr] = f2h_bits(h1);
            }
            float va = h0 * ka10 + h1 * ka11;
            float vb = h0 * ka20 + h1 * ka21;
            #pragma unroll
            for (int off = 1; off < 16; off <<= 1) {
                va += __shfl_xor(va, off, 64);
                vb += __shfl_xor(vb, off, 64);
            }
            if (lr == 0) { sh.abred[wv][rloc][0] = va; sh.abred[wv][rloc][1] = vb; }
        }
    }
    __syncthreads();
    if (t < 32) {
        int row = brow + t;
        if (row < n) {
            float sa = sh.abred[0][t][0] + sh.abred[1][t][0] + sh.abred[2][t][0] + sh.abred[3][t][0];
            float sb = sh.abred[0][t][1] + sh.abred[1][t][1] + sh.abred[2][t][1] + sh.abred[3][t][1];
            a[row] = sa; b[row] = sb;
        }
    }
}

// =================== K3: P2 — filtered bin scan + LDS bucket + fused agg =========
// EXACT twice-proven structure; only the h decode is fp16 now.
__global__ __launch_bounds__(256) void p2_agg_kernel(const unsigned short* __restrict__ h16,
                                                     const float* __restrict__ a,
                                                     const float* __restrict__ b,
                                                     const unsigned int* __restrict__ binbuf,
                                                     const int* __restrict__ bin_cursor,
                                                     float* __restrict__ out, int n) {
    int bin = blockIdx.x >> 5;        // SPLIT=32
    int q   = blockIdx.x & 31;        // which 16-node slice of the bin
    int node0 = bin * BINSZ + q * NPB;
    __shared__ unsigned short lbkt[NPB][CAP];   // 2 KB
    __shared__ int lcnt[NPB];

    int t = threadIdx.x;
    if (t < NPB) lcnt[t] = 0;
    __syncthreads();

    int ec = bin_cursor[bin]; if (ec > BCAP) ec = BCAP;
    const unsigned int* bp = binbuf + (size_t)bin * BCAP;
    for (int i = t; i < ec; i += 256) {
        unsigned int r = bp[i];
        int tl = (int)((r >> 16) & 0x1FF);
        if ((tl >> 4) == q) {
            int lv = tl & (NPB - 1);
            int p = atomicAdd(&lcnt[lv], 1);
            if (p < CAP) lbkt[lv][p] = (unsigned short)(r & 0xFFFFu);
        }
    }
    __syncthreads();

    int wid = t >> 6, lane = t & 63;
    int sub = lane >> 4, l16 = lane & 15;

    for (int lv = wid; lv < NPB; lv += 4) {
        int v = node0 + lv;
        if (v >= n) break;                        // wave-uniform
        int d = lcnt[lv]; if (d > CAP) d = CAP;
        float av = a[v];

        int nb = 0; float sv = 0.f;
        if (lane < d) {
            nb = (int)lbkt[lv][lane];
            float sc = av + b[nb];
            sc = (sc >= 0.f) ? sc : LEAKY * sc;   // leaky_relu
            sc = fminf(fmaxf(sc, -2.f), 2.f);     // clip
            sv = __expf(sc);
        }
        float ssum = sv;
        #pragma unroll
        for (int off = 32; off; off >>= 1) ssum += __shfl_xor(ssum, off, 64);

        float acc[8];
        #pragma unroll
        for (int i = 0; i < 8; ++i) acc[i] = 0.f;
        for (int j4 = 0; j4 < d; j4 += 4) {
            int j = j4 + sub;                     // <= 63 since d <= 64
            int nbj = __shfl(nb, j, 64);
            float wj = __shfl(sv, j, 64);
            uint4 hv = *(const uint4*)(h16 + (size_t)nbj * 128 + l16 * 8);
            union { uint4 u4; _Float16 h[8]; } cc; cc.u4 = hv;
            acc[0] += wj * (float)cc.h[0];
            acc[1] += wj * (float)cc.h[1];
            acc[2] += wj * (float)cc.h[2];
            acc[3] += wj * (float)cc.h[3];
            acc[4] += wj * (float)cc.h[4];
            acc[5] += wj * (float)cc.h[5];
            acc[6] += wj * (float)cc.h[6];
            acc[7] += wj * (float)cc.h[7];
        }
        #pragma unroll
        for (int i = 0; i < 8; ++i) {
            acc[i] += __shfl_xor(acc[i], 16, 64);
            acc[i] += __shfl_xor(acc[i], 32, 64);
        }
        float inv = 1.f / (ssum + EPSF);
        float o0 = (sub == 0) ? acc[0] : (sub == 1) ? acc[2] : (sub == 2) ? acc[4] : acc[6];
        float o1 = (sub == 0) ? acc[1] : (sub == 1) ? acc[3] : (sub == 2) ? acc[5] : acc[7];
        float2 o = make_float2(o0 * inv, o1 * inv);
        *(float2*)(out + (size_t)v * 128 + l16 * 8 + sub * 2) = o;
    }
}

// =================== fallback path (n > 65536): round-5 kernels (self-consistent bf16) ====
__global__ __launch_bounds__(256) void init_detect_big(const unsigned int* __restrict__ w,
                                                       int n_pairs, int n,
                                                       int* __restrict__ cursor,
                                                       int* __restrict__ flag) {
    int i = blockIdx.x * 256 + threadIdx.x;
    if (i < n) cursor[i] = i * CAP;
    if (blockIdx.x == 0) {
        __shared__ int any_sh;
        int t = threadIdx.x;
        if (t == 0) any_sh = 0;
        __syncthreads();
        unsigned int acc = 0;
        int lim = n_pairs < 8192 ? n_pairs : 8192;
        for (int k = t; k < lim; k += 256) acc |= w[2 * k + 1];
        if (__any(acc != 0)) { if ((t & 63) == 0) any_sh = 1; }
        __syncthreads();
        if (t == 0) *flag = any_sh ? 1 : 0;
    }
}

__global__ __launch_bounds__(256) void scatter_big(const void* __restrict__ eraw,
                                                   const int* __restrict__ flag,
                                                   int* __restrict__ cursor,
                                                   unsigned int* __restrict__ bucket,
                                                   int E, int scat_threads) {
    int tid = blockIdx.x * 256 + threadIdx.x;
    bool e32 = (*flag != 0);
    int tgts[EILP], nbrs[EILP];
    #pragma unroll
    for (int k = 0; k < EILP; ++k) {
        int e = tid + k * scat_threads;
        tgts[k] = -1;
        if (e < E) {
            if (e32) { uint2 q = ((const uint2*)eraw)[e]; tgts[k] = (int)q.x; nbrs[k] = (int)q.y; }
            else     { uint4 q = ((const uint4*)eraw)[e]; tgts[k] = (int)q.x; nbrs[k] = (int)q.z; }
        }
    }
    int slot[EILP];
    #pragma unroll
    for (int k = 0; k < EILP; ++k)
        if (tgts[k] >= 0) slot[k] = atomicAdd(&cursor[tgts[k]], 1);
    #pragma unroll
    for (int k = 0; k < EILP; ++k)
        if (tgts[k] >= 0 && slot[k] < tgts[k] * CAP + CAP) bucket[slot[k]] = (unsigned int)nbrs[k];
}

__global__ __launch_bounds__(256) void aggregate_big(const unsigned short* __restrict__ h16,
                                                     const float* __restrict__ a,
                                                     const float* __restrict__ b,
                                                     const int* __restrict__ cursor,
                                                     const unsigned int* __restrict__ bucket,
                                                     float* __restrict__ out, int n) {
    int wid = threadIdx.x >> 6, lane = threadIdx.x & 63;
    int v = blockIdx.x * 4 + wid;
    if (v >= n) return;
    int r0 = v * CAP;
    int d = cursor[v] - r0; d = d < CAP ? d : CAP;
    float av = a[v];
    int sub = lane >> 4, l16 = lane & 15;
    float ssum = 0.f;
    float acc[8];
    #pragma unroll
    for (int i = 0; i < 8; ++i) acc[i] = 0.f;
    int nb = 0; float sv = 0.f;
    if (lane < d) {
        nb = (int)bucket[r0 + lane];
        float sc = av + b[nb];
        sc = (sc >= 0.f) ? sc : LEAKY * sc;
        sc = fminf(fmaxf(sc, -2.f), 2.f);
        sv = __expf(sc);
    }
    ssum = sv;
    #pragma unroll
    for (int off = 32; off; off >>= 1) ssum += __shfl_xor(ssum, off, 64);
    for (int j4 = 0; j4 < d; j4 += 4) {
        int j = j4 + sub;
        int nbj = __shfl(nb, j, 64);
        float wj = __shfl(sv, j, 64);
        uint4 hv = *(const uint4*)(h16 + (size_t)nbj * 128 + l16 * 8);
        acc[0] += wj * __uint_as_float(hv.x << 16);
        acc[1] += wj * __uint_as_float(hv.x & 0xffff0000u);
        acc[2] += wj * __uint_as_float(hv.y << 16);
        acc[3] += wj * __uint_as_float(hv.y & 0xffff0000u);
        acc[4] += wj * __uint_as_float(hv.z << 16);
        acc[5] += wj * __uint_as_float(hv.z & 0xffff0000u);
        acc[6] += wj * __uint_as_float(hv.w << 16);
        acc[7] += wj * __uint_as_float(hv.w & 0xffff0000u);
    }
    #pragma unroll
    for (int i = 0; i < 8; ++i) {
        acc[i] += __shfl_xor(acc[i], 16, 64);
        acc[i] += __shfl_xor(acc[i], 32, 64);
    }
    float inv = 1.f / (ssum + EPSF);
    float o0 = (sub == 0) ? acc[0] : (sub == 1) ? acc[2] : (sub == 2) ? acc[4] : acc[6];
    float o1 = (sub == 0) ? acc[1] : (sub == 1) ? acc[3] : (sub == 2) ? acc[5] : acc[7];
    float2 o = make_float2(o0 * inv, o1 * inv);
    *(float2*)(out + (size_t)v * 128 + l16 * 8 + sub * 2) = o;
}

__global__ __launch_bounds__(256) void gemm_only_kernel(const float* __restrict__ X,
                                                        const float* __restrict__ W,
                                                        const float* __restrict__ ka,
                                                        unsigned short* __restrict__ h16,
                                                        float* __restrict__ a,
                                                        float* __restrict__ b, int n) {
    __shared__ float Xs[128][36];
    int brow = blockIdx.x * 32;
    int t = threadIdx.x;
    #pragma unroll
    for (int i = 0; i < 4; ++i) {
        int idx4 = t + 256 * i;
        int flat = idx4 * 4;
        int r = flat >> 7;
        int k = flat & 127;
        int row = brow + r;
        float4 v = make_float4(0.f, 0.f, 0.f, 0.f);
        if (row < n) v = *(const float4*)(X + (size_t)row * 128 + k);
        Xs[k + 0][r] = v.x; Xs[k + 1][r] = v.y; Xs[k + 2][r] = v.z; Xs[k + 3][r] = v.w;
    }
    __syncthreads();
    int c4 = (t & 31) * 4;
    int rg = (t >> 5) * 4;
    float acc[4][4] = {{0.f}};
    #pragma unroll 4
    for (int k = 0; k < 128; ++k) {
        float4 xv = *(const float4*)(&Xs[k][rg]);
        float4 wv = *(const float4*)(W + k * 128 + c4);
        float xr[4] = {xv.x, xv.y, xv.z, xv.w};
        float wc[4] = {wv.x, wv.y, wv.z, wv.w};
        #pragma unroll
        for (int r = 0; r < 4; ++r)
            #pragma unroll
            for (int c = 0; c < 4; ++c)
                acc[r][c] += xr[r] * wc[c];
    }
    #pragma unroll
    for (int r = 0; r < 4; ++r) {
        int row = brow + rg + r;
        if (row < n) {
            union { unsigned short u[4]; uint2 v; } pk;
            #pragma unroll
            for (int c = 0; c < 4; ++c) pk.u[c] = f2bf(acc[r][c]);
            *(uint2*)(h16 + (size_t)row * 128 + c4) = pk.v;
        }
    }
    float ka1[4], ka2[4];
    #pragma unroll
    for (int i = 0; i < 4; ++i) { ka1[i] = ka[c4 + i]; ka2[i] = ka[128 + c4 + i]; }
    #pragma unroll
    for (int r = 0; r < 4; ++r) {
        float pa = acc[r][0] * ka1[0] + acc[r][1] * ka1[1] + acc[r][2] * ka1[2] + acc[r][3] * ka1[3];
        float pb = acc[r][0] * ka2[0] + acc[r][1] * ka2[1] + acc[r][2] * ka2[2] + acc[r][3] * ka2[3];
        #pragma unroll
        for (int off = 16; off; off >>= 1) {
            pa += __shfl_xor(pa, off, 64);
            pb += __shfl_xor(pb, off, 64);
        }
        int row = brow + rg + r;
        if ((t & 31) == 0 && row < n) { a[row] = pa; b[row] = pb; }
    }
}

extern "C" void kernel_launch(void* const* d_in, const int* in_sizes, int n_in,
                              void* d_out, int out_size, void* d_ws, size_t ws_size,
                              hipStream_t stream) {
    const float* X     = (const float*)d_in[0];
    const void*  edges = d_in[1];
    const float* W     = (const float*)d_in[2];
    const float* ka    = (const float*)d_in[3];
    float* out = (float*)d_out;

    int n_nodes = in_sizes[0] / 128;
    int E       = in_sizes[1] / 2;

    char* ws = (char*)d_ws;
    size_t off = 0;
    auto alloc = [&](size_t bytes) { size_t o = off; off = (off + bytes + 255) & ~(size_t)255; return o; };
    unsigned short* h16 = (unsigned short*)(ws + alloc((size_t)n_nodes * 128 * 2));
    float* a = (float*)(ws + alloc((size_t)n_nodes * 4));
    float* b = (float*)(ws + alloc((size_t)n_nodes * 4));

    int gb = (n_nodes + 31) / 32;

    if (n_nodes <= 65536) {
        int nbins = (n_nodes + BINSZ - 1) / BINSZ;
        unsigned short* Wt16 = (unsigned short*)(ws + alloc(128 * 128 * 2));
        unsigned int* binbuf = (unsigned int*)(ws + alloc((size_t)nbins * BCAP * 4));
        int* bin_cursor = (int*)(ws + alloc((size_t)MAXBINS * 4));
        int* flag = (int*)(ws + alloc(4));

        int p1b = (E + TILE - 1) / TILE;
        init_kernel<<<64, 256, 0, stream>>>(W, (const unsigned int*)edges, E, Wt16, bin_cursor, flag);
        gemm_p1_kernel<<<gb + p1b, 256, 0, stream>>>(X, Wt16, ka, h16, a, b, n_nodes,
                                                     edges, flag, binbuf, bin_cursor, E, nbins, gb);
        p2_agg_kernel<<<nbins * SPLIT, 256, 0, stream>>>(h16, a, b, binbuf, bin_cursor, out, n_nodes);
    } else {
        int* cursor = (int*)(ws + alloc((size_t)n_nodes * 4));
        unsigned int* bucket = (unsigned int*)(ws + alloc((size_t)n_nodes * CAP * 4));
        int* flag = (int*)(ws + alloc(4));

        int ib = (n_nodes + 255) / 256;
        int sb = (E + EILP * 256 - 1) / (EILP * 256);
        int st = sb * 256;
        int ab = (n_nodes + 3) / 4;

        init_detect_big<<<ib, 256, 0, stream>>>((const unsigned int*)edges, E, n_nodes, cursor, flag);
        gemm_only_kernel<<<gb, 256, 0, stream>>>(X, W, ka, h16, a, b, n_nodes);
        scatter_big<<<sb, 256, 0, stream>>>(edges, flag, cursor, bucket, E, st);
        aggregate_big<<<ab, 256, 0, stream>>>(h16, a, b, cursor, bucket, out, n_nodes);
    }
}

// Round 17
// 89.502 us; speedup vs baseline: 1.0620x; 1.0620x over previous
//
#include <hip/hip_runtime.h>
#include <hip/hip_bf16.h>
#include <cstdint>

#define LEAKY 0.2f
#define EPSF 1e-7f

// ---- binned path (n <= 65536) ----
#define BINSHIFT 9
#define BINSZ 512
#define MAXBINS 128
#define BCAP 10240           // per-bin edge capacity (mean 8163, sd ~90)
#define TILE 4096            // edges per P1 block (16/thread)
#define SPLIT 32             // P2 blocks per bin
#define NPB 16               // nodes per P2 block
#define CAP 64               // per-node degree cap

// ---- fallback path (n > 65536) ----
#define EILP 8

__device__ __forceinline__ unsigned short f2bf(float x) {
    return __bfloat16_as_ushort(__float2bfloat16(x));
}
__device__ __forceinline__ unsigned short f2h_bits(float x) {
    union { _Float16 h; unsigned short s; } c; c.h = (_Float16)x; return c.s;
}

// =================== K1: zero bin cursors + edge dtype detect =====================
__global__ __launch_bounds__(256) void init_detect_kernel(const unsigned int* __restrict__ w,
                                                          int n_pairs,
                                                          int* __restrict__ bin_cursor,
                                                          int* __restrict__ flag) {
    __shared__ int any_sh;
    int t = threadIdx.x;
    if (t < MAXBINS) bin_cursor[t] = 0;
    if (t == 0) any_sh = 0;
    __syncthreads();
    unsigned int acc = 0;
    int lim = n_pairs < 8192 ? n_pairs : 8192;
    for (int k = t; k < lim; k += 256) acc |= w[2 * k + 1];
    if (__any(acc != 0)) {
        if ((t & 63) == 0) any_sh = 1;
    }
    __syncthreads();
    if (t == 0) *flag = any_sh ? 1 : 0;   // int64 edges: all-zero high halves -> 0
}

// =================== K2: fused f32 GEMM (blocks [0,gb)) + P1 binning (rest) =======
// GEMM is the R8-proven f32 VALU version (absmax 0.0039, deterministic); h stored fp16.
__global__ __launch_bounds__(256) void gemm_p1_kernel(const float* __restrict__ X,
                                                      const float* __restrict__ W,
                                                      const float* __restrict__ ka,
                                                      unsigned short* __restrict__ h16,
                                                      float* __restrict__ a,
                                                      float* __restrict__ b, int n,
                                                      const void* __restrict__ eraw,
                                                      const int* __restrict__ flag,
                                                      unsigned int* __restrict__ binbuf,
                                                      int* __restrict__ bin_cursor,
                                                      int E, int nbins, int gemm_blocks) {
    __shared__ union {
        float Xs[128][36];                                   // 18432 B (gemm)
        struct {
            unsigned int staged[TILE];                       // 16384 B
            int hist[MAXBINS], sbase[MAXBINS], scur[MAXBINS], gpos[MAXBINS]; // 2048 B
        } p1;
    } sh;

    int t = threadIdx.x;

    if ((int)blockIdx.x >= gemm_blocks) {
        // ---------------- P1: partition edges into bins, coalesced output ---------
        int pb = (int)blockIdx.x - gemm_blocks;
        int tile0 = pb * TILE;
        int cnt_t = E - tile0; if (cnt_t > TILE) cnt_t = TILE; if (cnt_t < 0) cnt_t = 0;
        bool e32 = (*flag != 0);

        for (int i = t; i < MAXBINS; i += 256) sh.p1.hist[i] = 0;
        __syncthreads();

        unsigned int rec[16]; int bn[16];
        #pragma unroll
        for (int k = 0; k < 16; ++k) {
            int ofs = t + k * 256;
            bn[k] = -1;
            if (ofs < cnt_t) {
                int e = tile0 + ofs;
                unsigned int tgt, nbr;
                if (e32) {
                    uint2 q = ((const uint2*)eraw)[e];
                    tgt = q.x; nbr = q.y;
                } else {
                    uint4 q = ((const uint4*)eraw)[e];   // int64 pair: lows at x,z
                    tgt = q.x; nbr = q.z;
                }
                int bb = (int)(tgt >> BINSHIFT);
                rec[k] = ((unsigned int)bb << 25) | ((tgt & (BINSZ - 1)) << 16) | (nbr & 0xFFFFu);
                bn[k] = bb;
                atomicAdd(&sh.p1.hist[bb], 1);
            }
        }
        __syncthreads();

        if (t < 64) {    // exclusive scan over 128 bins, 2/lane
            int h0 = sh.p1.hist[t], h1 = sh.p1.hist[t + 64];
            int x0 = h0, x1 = h1;
            #pragma unroll
            for (int off = 1; off < 64; off <<= 1) {
                int y = __shfl_up(x0, off, 64); if (t >= off) x0 += y;
            }
            int tot0 = __shfl(x0, 63, 64);
            #pragma unroll
            for (int off = 1; off < 64; off <<= 1) {
                int y = __shfl_up(x1, off, 64); if (t >= off) x1 += y;
            }
            x1 += tot0;
            sh.p1.sbase[t] = x0 - h0;
            sh.p1.sbase[t + 64] = x1 - h1;
        }
        __syncthreads();
        if (t < MAXBINS) sh.p1.scur[t] = sh.p1.sbase[t];
        if (t < nbins) {
            int c = sh.p1.hist[t];
            sh.p1.gpos[t] = c ? atomicAdd(&bin_cursor[t], c) : 0;   // one atomic/bin/block
        }
        __syncthreads();

        #pragma unroll
        for (int k = 0; k < 16; ++k) {
            if (bn[k] >= 0) {
                int pos = atomicAdd(&sh.p1.scur[bn[k]], 1);
                sh.p1.staged[pos] = rec[k];
            }
        }
        __syncthreads();

        for (int i = t; i < cnt_t; i += 256) {
            unsigned int r = sh.p1.staged[i];
            int bb = (int)(r >> 25);
            int g = sh.p1.gpos[bb] + (i - sh.p1.sbase[bb]);
            if (g < BCAP) binbuf[(size_t)bb * BCAP + g] = r & 0x01FFFFFFu;
        }
        return;
    }

    // ---------------- f32 VALU GEMM: 32 rows x 128 cols per block -----------------
    int brow = blockIdx.x * 32;

    #pragma unroll
    for (int i = 0; i < 4; ++i) {
        int idx4 = t + 256 * i;
        int flat = idx4 * 4;
        int r = flat >> 7;
        int k = flat & 127;
        int row = brow + r;
        float4 v = make_float4(0.f, 0.f, 0.f, 0.f);
        if (row < n) v = *(const float4*)(X + (size_t)row * 128 + k);
        sh.Xs[k + 0][r] = v.x; sh.Xs[k + 1][r] = v.y; sh.Xs[k + 2][r] = v.z; sh.Xs[k + 3][r] = v.w;
    }
    __syncthreads();

    int c4 = (t & 31) * 4;
    int rg = (t >> 5) * 4;
    float acc[4][4] = {{0.f}};

    #pragma unroll 4
    for (int k = 0; k < 128; ++k) {
        float4 xv = *(const float4*)(&sh.Xs[k][rg]);
        float4 wv = *(const float4*)(W + k * 128 + c4);
        float xr[4] = {xv.x, xv.y, xv.z, xv.w};
        float wc[4] = {wv.x, wv.y, wv.z, wv.w};
        #pragma unroll
        for (int r = 0; r < 4; ++r)
            #pragma unroll
            for (int c = 0; c < 4; ++c)
                acc[r][c] += xr[r] * wc[c];
    }

    // epilogue 1: h store as fp16 (8B per row per thread)
    #pragma unroll
    for (int r = 0; r < 4; ++r) {
        int row = brow + rg + r;
        if (row < n) {
            union { unsigned short u[4]; uint2 v; } pk;
            #pragma unroll
            for (int c = 0; c < 4; ++c) pk.u[c] = f2h_bits(acc[r][c]);
            *(uint2*)(h16 + (size_t)row * 128 + c4) = pk.v;
        }
    }

    // epilogue 2: per-node attention scalars from exact f32 acc
    float ka1[4], ka2[4];
    #pragma unroll
    for (int i = 0; i < 4; ++i) { ka1[i] = ka[c4 + i]; ka2[i] = ka[128 + c4 + i]; }
    #pragma unroll
    for (int r = 0; r < 4; ++r) {
        float pa = acc[r][0] * ka1[0] + acc[r][1] * ka1[1] + acc[r][2] * ka1[2] + acc[r][3] * ka1[3];
        float pb = acc[r][0] * ka2[0] + acc[r][1] * ka2[1] + acc[r][2] * ka2[2] + acc[r][3] * ka2[3];
        #pragma unroll
        for (int off = 16; off; off >>= 1) {
            pa += __shfl_xor(pa, off, 64);
            pb += __shfl_xor(pb, off, 64);
        }
        int row = brow + rg + r;
        if ((t & 31) == 0 && row < n) { a[row] = pa; b[row] = pb; }
    }
}

// =================== K3: P2 — filtered bin scan (uint4) + LDS bucket + fused agg ==
__global__ __launch_bounds__(256) void p2_agg_kernel(const unsigned short* __restrict__ h16,
                                                     const float* __restrict__ a,
                                                     const float* __restrict__ b,
                                                     const unsigned int* __restrict__ binbuf,
                                                     const int* __restrict__ bin_cursor,
                                                     float* __restrict__ out, int n) {
    int bin = blockIdx.x >> 5;        // SPLIT=32
    int q   = blockIdx.x & 31;        // which 16-node slice of the bin
    int node0 = bin * BINSZ + q * NPB;
    __shared__ unsigned short lbkt[NPB][CAP];   // 2 KB
    __shared__ int lcnt[NPB];

    int t = threadIdx.x;
    if (t < NPB) lcnt[t] = 0;
    __syncthreads();

    int ec = bin_cursor[bin]; if (ec > BCAP) ec = BCAP;
    const unsigned int* bp = binbuf + (size_t)bin * BCAP;

    // vectorized filter scan: 4 records per 16B load (bp is 16B-aligned)
    int ec4 = ec >> 2;
    const uint4* bp4 = (const uint4*)bp;
    for (int i = t; i < ec4; i += 256) {
        uint4 r4 = bp4[i];
        {
            unsigned int r = r4.x;
            int tl = (int)((r >> 16) & 0x1FF);
            if ((tl >> 4) == q) {
                int lv = tl & (NPB - 1);
                int p = atomicAdd(&lcnt[lv], 1);
                if (p < CAP) lbkt[lv][p] = (unsigned short)(r & 0xFFFFu);
            }
        }
        {
            unsigned int r = r4.y;
            int tl = (int)((r >> 16) & 0x1FF);
            if ((tl >> 4) == q) {
                int lv = tl & (NPB - 1);
                int p = atomicAdd(&lcnt[lv], 1);
                if (p < CAP) lbkt[lv][p] = (unsigned short)(r & 0xFFFFu);
            }
        }
        {
            unsigned int r = r4.z;
            int tl = (int)((r >> 16) & 0x1FF);
            if ((tl >> 4) == q) {
                int lv = tl & (NPB - 1);
                int p = atomicAdd(&lcnt[lv], 1);
                if (p < CAP) lbkt[lv][p] = (unsigned short)(r & 0xFFFFu);
            }
        }
        {
            unsigned int r = r4.w;
            int tl = (int)((r >> 16) & 0x1FF);
            if ((tl >> 4) == q) {
                int lv = tl & (NPB - 1);
                int p = atomicAdd(&lcnt[lv], 1);
                if (p < CAP) lbkt[lv][p] = (unsigned short)(r & 0xFFFFu);
            }
        }
    }
    for (int i = (ec4 << 2) + t; i < ec; i += 256) {   // tail (ec & 3 records)
        unsigned int r = bp[i];
        int tl = (int)((r >> 16) & 0x1FF);
        if ((tl >> 4) == q) {
            int lv = tl & (NPB - 1);
            int p = atomicAdd(&lcnt[lv], 1);
            if (p < CAP) lbkt[lv][p] = (unsigned short)(r & 0xFFFFu);
        }
    }
    __syncthreads();

    int wid = t >> 6, lane = t & 63;
    int sub = lane >> 4, l16 = lane & 15;

    for (int lv = wid; lv < NPB; lv += 4) {
        int v = node0 + lv;
        if (v >= n) break;                        // wave-uniform
        int d = lcnt[lv]; if (d > CAP) d = CAP;
        float av = a[v];

        int nb = 0; float sv = 0.f;
        if (lane < d) {
            nb = (int)lbkt[lv][lane];
            float sc = av + b[nb];
            sc = (sc >= 0.f) ? sc : LEAKY * sc;   // leaky_relu
            sc = fminf(fmaxf(sc, -2.f), 2.f);     // clip
            sv = __expf(sc);
        }
        float ssum = sv;
        #pragma unroll
        for (int off = 32; off; off >>= 1) ssum += __shfl_xor(ssum, off, 64);

        float acc[8];
        #pragma unroll
        for (int i = 0; i < 8; ++i) acc[i] = 0.f;
        for (int j4 = 0; j4 < d; j4 += 4) {
            int j = j4 + sub;                     // <= 63 since d <= 64
            int nbj = __shfl(nb, j, 64);
            float wj = __shfl(sv, j, 64);
            uint4 hv = *(const uint4*)(h16 + (size_t)nbj * 128 + l16 * 8);
            union { uint4 u4; _Float16 h[8]; } cc; cc.u4 = hv;
            acc[0] += wj * (float)cc.h[0];
            acc[1] += wj * (float)cc.h[1];
            acc[2] += wj * (float)cc.h[2];
            acc[3] += wj * (float)cc.h[3];
            acc[4] += wj * (float)cc.h[4];
            acc[5] += wj * (float)cc.h[5];
            acc[6] += wj * (float)cc.h[6];
            acc[7] += wj * (float)cc.h[7];
        }
        #pragma unroll
        for (int i = 0; i < 8; ++i) {
            acc[i] += __shfl_xor(acc[i], 16, 64);
            acc[i] += __shfl_xor(acc[i], 32, 64);
        }
        float inv = 1.f / (ssum + EPSF);
        float o0 = (sub == 0) ? acc[0] : (sub == 1) ? acc[2] : (sub == 2) ? acc[4] : acc[6];
        float o1 = (sub == 0) ? acc[1] : (sub == 1) ? acc[3] : (sub == 2) ? acc[5] : acc[7];
        float2 o = make_float2(o0 * inv, o1 * inv);
        *(float2*)(out + (size_t)v * 128 + l16 * 8 + sub * 2) = o;
    }
}

// =================== fallback path (n > 65536): round-5 kernels ==================
__global__ __launch_bounds__(256) void init_detect_big(const unsigned int* __restrict__ w,
                                                       int n_pairs, int n,
                                                       int* __restrict__ cursor,
                                                       int* __restrict__ flag) {
    int i = blockIdx.x * 256 + threadIdx.x;
    if (i < n) cursor[i] = i * CAP;
    if (blockIdx.x == 0) {
        __shared__ int any_sh;
        int t = threadIdx.x;
        if (t == 0) any_sh = 0;
        __syncthreads();
        unsigned int acc = 0;
        int lim = n_pairs < 8192 ? n_pairs : 8192;
        for (int k = t; k < lim; k += 256) acc |= w[2 * k + 1];
        if (__any(acc != 0)) { if ((t & 63) == 0) any_sh = 1; }
        __syncthreads();
        if (t == 0) *flag = any_sh ? 1 : 0;
    }
}

__global__ __launch_bounds__(256) void scatter_big(const void* __restrict__ eraw,
                                                   const int* __restrict__ flag,
                                                   int* __restrict__ cursor,
                                                   unsigned int* __restrict__ bucket,
                                                   int E, int scat_threads) {
    int tid = blockIdx.x * 256 + threadIdx.x;
    bool e32 = (*flag != 0);
    int tgts[EILP], nbrs[EILP];
    #pragma unroll
    for (int k = 0; k < EILP; ++k) {
        int e = tid + k * scat_threads;
        tgts[k] = -1;
        if (e < E) {
            if (e32) { uint2 q = ((const uint2*)eraw)[e]; tgts[k] = (int)q.x; nbrs[k] = (int)q.y; }
            else     { uint4 q = ((const uint4*)eraw)[e]; tgts[k] = (int)q.x; nbrs[k] = (int)q.z; }
        }
    }
    int slot[EILP];
    #pragma unroll
    for (int k = 0; k < EILP; ++k)
        if (tgts[k] >= 0) slot[k] = atomicAdd(&cursor[tgts[k]], 1);
    #pragma unroll
    for (int k = 0; k < EILP; ++k)
        if (tgts[k] >= 0 && slot[k] < tgts[k] * CAP + CAP) bucket[slot[k]] = (unsigned int)nbrs[k];
}

__global__ __launch_bounds__(256) void aggregate_big(const unsigned short* __restrict__ h16,
                                                     const float* __restrict__ a,
                                                     const float* __restrict__ b,
                                                     const int* __restrict__ cursor,
                                                     const unsigned int* __restrict__ bucket,
                                                     float* __restrict__ out, int n) {
    int wid = threadIdx.x >> 6, lane = threadIdx.x & 63;
    int v = blockIdx.x * 4 + wid;
    if (v >= n) return;
    int r0 = v * CAP;
    int d = cursor[v] - r0; d = d < CAP ? d : CAP;
    float av = a[v];
    int sub = lane >> 4, l16 = lane & 15;
    float ssum = 0.f;
    float acc[8];
    #pragma unroll
    for (int i = 0; i < 8; ++i) acc[i] = 0.f;
    int nb = 0; float sv = 0.f;
    if (lane < d) {
        nb = (int)bucket[r0 + lane];
        float sc = av + b[nb];
        sc = (sc >= 0.f) ? sc : LEAKY * sc;
        sc = fminf(fmaxf(sc, -2.f), 2.f);
        sv = __expf(sc);
    }
    ssum = sv;
    #pragma unroll
    for (int off = 32; off; off >>= 1) ssum += __shfl_xor(ssum, off, 64);
    for (int j4 = 0; j4 < d; j4 += 4) {
        int j = j4 + sub;
        int nbj = __shfl(nb, j, 64);
        float wj = __shfl(sv, j, 64);
        uint4 hv = *(const uint4*)(h16 + (size_t)nbj * 128 + l16 * 8);
        union { uint4 u4; _Float16 h[8]; } cc; cc.u4 = hv;
        acc[0] += wj * (float)cc.h[0];
        acc[1] += wj * (float)cc.h[1];
        acc[2] += wj * (float)cc.h[2];
        acc[3] += wj * (float)cc.h[3];
        acc[4] += wj * (float)cc.h[4];
        acc[5] += wj * (float)cc.h[5];
        acc[6] += wj * (float)cc.h[6];
        acc[7] += wj * (float)cc.h[7];
    }
    #pragma unroll
    for (int i = 0; i < 8; ++i) {
        acc[i] += __shfl_xor(acc[i], 16, 64);
        acc[i] += __shfl_xor(acc[i], 32, 64);
    }
    float inv = 1.f / (ssum + EPSF);
    float o0 = (sub == 0) ? acc[0] : (sub == 1) ? acc[2] : (sub == 2) ? acc[4] : acc[6];
    float o1 = (sub == 0) ? acc[1] : (sub == 1) ? acc[3] : (sub == 2) ? acc[5] : acc[7];
    float2 o = make_float2(o0 * inv, o1 * inv);
    *(float2*)(out + (size_t)v * 128 + l16 * 8 + sub * 2) = o;
}

__global__ __launch_bounds__(256) void gemm_only_kernel(const float* __restrict__ X,
                                                        const float* __restrict__ W,
                                                        const float* __restrict__ ka,
                                                        unsigned short* __restrict__ h16,
                                                        float* __restrict__ a,
                                                        float* __restrict__ b, int n) {
    __shared__ float Xs[128][36];
    int brow = blockIdx.x * 32;
    int t = threadIdx.x;
    #pragma unroll
    for (int i = 0; i < 4; ++i) {
        int idx4 = t + 256 * i;
        int flat = idx4 * 4;
        int r = flat >> 7;
        int k = flat & 127;
        int row = brow + r;
        float4 v = make_float4(0.f, 0.f, 0.f, 0.f);
        if (row < n) v = *(const float4*)(X + (size_t)row * 128 + k);
        Xs[k + 0][r] = v.x; Xs[k + 1][r] = v.y; Xs[k + 2][r] = v.z; Xs[k + 3][r] = v.w;
    }
    __syncthreads();
    int c4 = (t & 31) * 4;
    int rg = (t >> 5) * 4;
    float acc[4][4] = {{0.f}};
    #pragma unroll 4
    for (int k = 0; k < 128; ++k) {
        float4 xv = *(const float4*)(&Xs[k][rg]);
        float4 wv = *(const float4*)(W + k * 128 + c4);
        float xr[4] = {xv.x, xv.y, xv.z, xv.w};
        float wc[4] = {wv.x, wv.y, wv.z, wv.w};
        #pragma unroll
        for (int r = 0; r < 4; ++r)
            #pragma unroll
            for (int c = 0; c < 4; ++c)
                acc[r][c] += xr[r] * wc[c];
    }
    #pragma unroll
    for (int r = 0; r < 4; ++r) {
        int row = brow + rg + r;
        if (row < n) {
            union { unsigned short u[4]; uint2 v; } pk;
            #pragma unroll
            for (int c = 0; c < 4; ++c) pk.u[c] = f2h_bits(acc[r][c]);
            *(uint2*)(h16 + (size_t)row * 128 + c4) = pk.v;
        }
    }
    float ka1[4], ka2[4];
    #pragma unroll
    for (int i = 0; i < 4; ++i) { ka1[i] = ka[c4 + i]; ka2[i] = ka[128 + c4 + i]; }
    #pragma unroll
    for (int r = 0; r < 4; ++r) {
        float pa = acc[r][0] * ka1[0] + acc[r][1] * ka1[1] + acc[r][2] * ka1[2] + acc[r][3] * ka1[3];
        float pb = acc[r][0] * ka2[0] + acc[r][1] * ka2[1] + acc[r][2] * ka2[2] + acc[r][3] * ka2[3];
        #pragma unroll
        for (int off = 16; off; off >>= 1) {
            pa += __shfl_xor(pa, off, 64);
            pb += __shfl_xor(pb, off, 64);
        }
        int row = brow + rg + r;
        if ((t & 31) == 0 && row < n) { a[row] = pa; b[row] = pb; }
    }
}

extern "C" void kernel_launch(void* const* d_in, const int* in_sizes, int n_in,
                              void* d_out, int out_size, void* d_ws, size_t ws_size,
                              hipStream_t stream) {
    const float* X     = (const float*)d_in[0];
    const void*  edges = d_in[1];
    const float* W     = (const float*)d_in[2];
    const float* ka    = (const float*)d_in[3];
    float* out = (float*)d_out;

    int n_nodes = in_sizes[0] / 128;
    int E       = in_sizes[1] / 2;

    char* ws = (char*)d_ws;
    size_t off = 0;
    auto alloc = [&](size_t bytes) { size_t o = off; off = (off + bytes + 255) & ~(size_t)255; return o; };
    unsigned short* h16 = (unsigned short*)(ws + alloc((size_t)n_nodes * 128 * 2));
    float* a = (float*)(ws + alloc((size_t)n_nodes * 4));
    float* b = (float*)(ws + alloc((size_t)n_nodes * 4));

    int gb = (n_nodes + 31) / 32;

    if (n_nodes <= 65536) {
        int nbins = (n_nodes + BINSZ - 1) / BINSZ;
        unsigned int* binbuf = (unsigned int*)(ws + alloc((size_t)nbins * BCAP * 4));
        int* bin_cursor = (int*)(ws + alloc((size_t)MAXBINS * 4));
        int* flag = (int*)(ws + alloc(4));

        int p1b = (E + TILE - 1) / TILE;
        init_detect_kernel<<<1, 256, 0, stream>>>((const unsigned int*)edges, E, bin_cursor, flag);
        gemm_p1_kernel<<<gb + p1b, 256, 0, stream>>>(X, W, ka, h16, a, b, n_nodes,
                                                     edges, flag, binbuf, bin_cursor, E, nbins, gb);
        p2_agg_kernel<<<nbins * SPLIT, 256, 0, stream>>>(h16, a, b, binbuf, bin_cursor, out, n_nodes);
    } else {
        int* cursor = (int*)(ws + alloc((size_t)n_nodes * 4));
        unsigned int* bucket = (unsigned int*)(ws + alloc((size_t)n_nodes * CAP * 4));
        int* flag = (int*)(ws + alloc(4));

        int ib = (n_nodes + 255) / 256;
        int sb = (E + EILP * 256 - 1) / (EILP * 256);
        int st = sb * 256;
        int ab = (n_nodes + 3) / 4;

        init_detect_big<<<ib, 256, 0, stream>>>((const unsigned int*)edges, E, n_nodes, cursor, flag);
        gemm_only_kernel<<<gb, 256, 0, stream>>>(X, W, ka, h16, a, b, n_nodes);
        scatter_big<<<sb, 256, 0, stream>>>(edges, flag, cursor, bucket, E, st);
        aggregate_big<<<ab, 256, 0, stream>>>(h16, a, b, cursor, bucket, out, n_nodes);
    }
}